// Round 8
// baseline (932.778 us; speedup 1.0000x reference)
//
#include <hip/hip_runtime.h>
#include <hip/hip_bf16.h>
#include <math.h>

// B=1, S=512, N=384, D=64, H=32, DP=128, DQK=64
// ws layout (float offsets)
#define WS_X        0u          // x f32 [196608][64]                 = 12582912
#define WS_AEXT     12582912u   // AH frag bf16 [768*16][64][8] = 3145728 f, then AL same
#define WS_BEXT     18874368u   // BH, BL same
#define WS_QG       25165824u   // qg [2][384][64] = 49152
#define WS_SQG      25214976u   // [768]
#define WS_SQB      25215744u   // [768]
#define WS_PART     25216512u   // partial dots [2][512][3] = 3072
#define WS_WSQ      25219584u   // [512]
#define WS_BPP      25220096u   // [256]
#define WS_WPF      25220352u   // WpF bf16 frag-layout [2][16][32][64][8] = 262144 f

typedef __attribute__((ext_vector_type(8))) short bf16x8;
typedef __attribute__((ext_vector_type(4))) float f32x4;

union U4B8 { uint4 u4; unsigned u[4]; bf16x8 v; };

__device__ __forceinline__ unsigned short f2b(float x) {
    __hip_bfloat16 b = __float2bfloat16(x);
    return *reinterpret_cast<unsigned short*>(&b);
}
__device__ __forceinline__ float b2f(unsigned short u) {
    __hip_bfloat16 b = *reinterpret_cast<__hip_bfloat16*>(&u);
    return __bfloat162float(b);
}

#define GLDS(g, l) __builtin_amdgcn_global_load_lds(                                   \
    (const __attribute__((address_space(1))) unsigned int*)(g),                        \
    (__attribute__((address_space(3))) unsigned int*)(l), 16, 0, 0)

// ---------------- K1: LayerNorm over D=64, float4-vectorized (16 rows/block) ----------------
__global__ __launch_bounds__(256) void k1_ln(const float* __restrict__ msa,
                                             const float* __restrict__ g,
                                             const float* __restrict__ bb,
                                             float* __restrict__ x) {
    int row = blockIdx.x * 16 + (threadIdx.x >> 4);
    int l16 = threadIdx.x & 15;
    float4 v = ((const float4*)msa)[(size_t)row * 16 + l16];
    float sum = v.x + v.y + v.z + v.w;
    #pragma unroll
    for (int m = 1; m < 16; m <<= 1) sum += __shfl_xor(sum, m);
    float mean = sum * (1.0f / 64.0f);
    float4 dv = make_float4(v.x - mean, v.y - mean, v.z - mean, v.w - mean);
    float sq = dv.x * dv.x + dv.y * dv.y + dv.z * dv.z + dv.w * dv.w;
    #pragma unroll
    for (int m = 1; m < 16; m <<= 1) sq += __shfl_xor(sq, m);
    float r = rsqrtf(sq * (1.0f / 64.0f) + 1e-5f);
    float4 g4 = ((const float4*)g)[l16];
    float4 b4 = ((const float4*)bb)[l16];
    ((float4*)x)[(size_t)row * 16 + l16] = make_float4(
        dv.x * r * g4.x + b4.x, dv.y * r * g4.y + b4.y,
        dv.z * r * g4.z + b4.z, dv.w * r * g4.w + b4.w);
}

// ---------------- K2: q projection + LN, emit qg = qn*kn_g, Sqg, Sqb ----------------
__global__ __launch_bounds__(128) void k2_q(const float* __restrict__ x,
                                            const float* __restrict__ Wq,
                                            const float* __restrict__ qg_,
                                            const float* __restrict__ qb_,
                                            const float* __restrict__ kg_,
                                            const float* __restrict__ kb_,
                                            float* __restrict__ qgOut,
                                            float* __restrict__ SqgOut,
                                            float* __restrict__ SqbOut) {
    int n = blockIdx.x;
    int tt = threadIdx.x >> 6;
    int d = threadIdx.x & 63;
    const float* xr = x + (size_t)n * 64;
    const float* w  = Wq + (size_t)(tt * 64 + d) * 64;
    float acc = 0.f;
    #pragma unroll 8
    for (int dd = 0; dd < 64; ++dd) acc += xr[dd] * w[dd];
    float sum = acc;
    #pragma unroll
    for (int m = 1; m < 64; m <<= 1) sum += __shfl_xor(sum, m);
    float mean = sum * (1.0f / 64.0f);
    float dv = acc - mean;
    float sq = dv * dv;
    #pragma unroll
    for (int m = 1; m < 64; m <<= 1) sq += __shfl_xor(sq, m);
    float r = rsqrtf(sq * (1.0f / 64.0f) + 1e-5f);
    float qnv = dv * r * qg_[d] + qb_[d];
    float qgv = qnv * kg_[d];
    float sb  = qnv * kb_[d];
    float sg  = qgv;
    #pragma unroll
    for (int m = 1; m < 64; m <<= 1) { sg += __shfl_xor(sg, m); sb += __shfl_xor(sb, m); }
    qgOut[(size_t)(tt * 384 + n) * 64 + d] = qgv;
    if (d == 0) { SqgOut[tt * 384 + n] = sg; SqbOut[tt * 384 + n] = sb; }
}

// ---------------- gemm_k3: kraw tile (fp32 GEMM) + LN-dot epilogue -> partials ----------------
__global__ __launch_bounds__(256) void gemm_k3(const float* __restrict__ X,
                                               const float* __restrict__ Wk,
                                               const float* __restrict__ qg,
                                               const float* __restrict__ Sqg,
                                               const float* __restrict__ Sqb,
                                               float* __restrict__ part) {
    __shared__ __align__(16) char smem[65536];
    float (*AsT)[132] = (float(*)[132])smem;
    float (*BsT)[132] = (float(*)[132])(smem + 16896);
    float* kbuf = (float*)smem;   // aliases AsT/BsT after GEMM completes

    int t  = threadIdx.x;
    int m0 = blockIdx.x * 128;
    int s  = m0 / 384;
    int nchunk = (m0 - s * 384) >> 7;
    int tr = t >> 4, tc = t & 15;
    float acc[8][8] = {};
    int rrow = t >> 3;
    int kk   = (t & 7) * 4;
    for (int k0 = 0; k0 < 64; k0 += 32) {
        #pragma unroll
        for (int l = 0; l < 4; ++l) {
            int row = rrow + 32 * l;
            float4 va = *(const float4*)(X + (size_t)(m0 + row) * 64 + k0 + kk);
            AsT[kk + 0][row] = va.x; AsT[kk + 1][row] = va.y;
            AsT[kk + 2][row] = va.z; AsT[kk + 3][row] = va.w;
            float4 vb = *(const float4*)(Wk + (size_t)row * 64 + k0 + kk);
            BsT[kk + 0][row] = vb.x; BsT[kk + 1][row] = vb.y;
            BsT[kk + 2][row] = vb.z; BsT[kk + 3][row] = vb.w;
        }
        __syncthreads();
        #pragma unroll 4
        for (int k = 0; k < 32; ++k) {
            float a[8], b[8];
            *(float4*)&a[0] = *(const float4*)&AsT[k][tr * 8];
            *(float4*)&a[4] = *(const float4*)&AsT[k][tr * 8 + 4];
            *(float4*)&b[0] = *(const float4*)&BsT[k][tc * 8];
            *(float4*)&b[4] = *(const float4*)&BsT[k][tc * 8 + 4];
            #pragma unroll
            for (int q = 0; q < 8; ++q)
                #pragma unroll
                for (int j = 0; j < 8; ++j)
                    acc[q][j] += a[q] * b[j];
        }
        __syncthreads();
    }
    #pragma unroll
    for (int q = 0; q < 8; ++q) {
        int m = tr * 8 + q;
        int swz = (m & 15) << 4;
        int b0 = m * 512 + (((tc * 2) * 16) ^ swz);
        int b1 = m * 512 + (((tc * 2 + 1) * 16) ^ swz);
        *(float4*)((char*)kbuf + b0) = make_float4(acc[q][0], acc[q][1], acc[q][2], acc[q][3]);
        *(float4*)((char*)kbuf + b1) = make_float4(acc[q][4], acc[q][5], acc[q][6], acc[q][7]);
    }
    __syncthreads();
    int r  = t & 127;
    int tt = t >> 7;
    int n  = nchunk * 128 + r;
    const char* base = (const char*)kbuf + r * 512;
    const float4* qgp = (const float4*)(qg + ((size_t)(tt * 384 + n)) * 64);
    int swz = (r & 15) << 4;
    float s1 = 0.f, s2 = 0.f, s3 = 0.f;
    #pragma unroll
    for (int i = 0; i < 16; ++i) {
        float4 kv = *(const float4*)(base + ((((tt * 16 + i) * 16) ^ swz)));
        float4 qv = qgp[i];
        s1 += kv.x + kv.y + kv.z + kv.w;
        s2 += kv.x * kv.x + kv.y * kv.y + kv.z * kv.z + kv.w * kv.w;
        s3 += kv.x * qv.x + kv.y * qv.y + kv.z * qv.z + kv.w * qv.w;
    }
    float mu  = s1 * (1.0f / 64.0f);
    float var = s2 * (1.0f / 64.0f) - mu * mu;
    float rln = rsqrtf(var + 1e-5f);
    float dot = rln * (s3 - mu * Sqg[tt * 384 + n]) + Sqb[tt * 384 + n];
    #pragma unroll
    for (int m = 1; m < 64; m <<= 1) dot += __shfl_xor(dot, m);
    __syncthreads();
    if ((t & 63) == 0) kbuf[t >> 6] = dot;
    __syncthreads();
    if (t == 0) part[((size_t)0 * 512 + s) * 3 + nchunk] = kbuf[0] + kbuf[1];
    if (t == 1) part[((size_t)1 * 512 + s) * 3 + nchunk] = kbuf[2] + kbuf[3];
}

// ---------------- K4: lambda, softmax over s, sqrt weights (reads partials) ----------------
__global__ __launch_bounds__(512) void k4_softmax(const float* __restrict__ part,
                                                  const float* __restrict__ lq1,
                                                  const float* __restrict__ lk1,
                                                  const float* __restrict__ lq2,
                                                  const float* __restrict__ lk2,
                                                  float* __restrict__ wsq) {
    int s = threadIdx.x;
    float l1 = 0.f, l2 = 0.f;
    for (int i = 0; i < 64; ++i) { l1 += lq1[i] * lk1[i]; l2 += lq2[i] * lk2[i]; }
    float lam = expf(l1) - expf(l2) + 1.0f;
    const float c = 0.125f / 384.0f;
    float a0 = (part[s * 3] + part[s * 3 + 1] + part[s * 3 + 2]) * c;
    float a1 = (part[(512 + s) * 3] + part[(512 + s) * 3 + 1] + part[(512 + s) * 3 + 2]) * c;
    float v = a0 - lam * a1;
    __shared__ float red[512];
    red[s] = v;
    __syncthreads();
    for (int off = 256; off > 0; off >>= 1) {
        if (s < off) red[s] = fmaxf(red[s], red[s + off]);
        __syncthreads();
    }
    float mx = red[0];
    __syncthreads();
    float e = expf(v - mx);
    red[s] = e;
    __syncthreads();
    for (int off = 256; off > 0; off >>= 1) {
        if (s < off) red[s] += red[s + off];
        __syncthreads();
    }
    wsq[s] = sqrtf(e / red[0] + 1e-32f);
}

// ---------------- K5: build A/B hi-lo splits in MFMA-frag-native layout ----------------
__global__ __launch_bounds__(256) void k5_ab(const float* __restrict__ x,
                                             const float* __restrict__ Wl,
                                             const float* __restrict__ Wr,
                                             const float* __restrict__ wsq,
                                             unsigned short* __restrict__ AHo,
                                             unsigned short* __restrict__ ALo,
                                             unsigned short* __restrict__ BHo,
                                             unsigned short* __restrict__ BLo) {
    int i  = blockIdx.x;
    int s0 = blockIdx.y * 64;
    int t  = threadIdx.x;
    __shared__ __align__(16) float wl[2048], wr[2048];
    __shared__ float xT[64][69];
    ((float4*)wl)[t * 2]     = ((const float4*)Wl)[t * 2];
    ((float4*)wl)[t * 2 + 1] = ((const float4*)Wl)[t * 2 + 1];
    ((float4*)wr)[t * 2]     = ((const float4*)Wr)[t * 2];
    ((float4*)wr)[t * 2 + 1] = ((const float4*)Wr)[t * 2 + 1];
    {
        int s_l = t >> 2, d0 = (t & 3) * 16;
        const float* xr = x + ((size_t)(s0 + s_l) * 384 + i) * 64 + d0;
        #pragma unroll
        for (int j = 0; j < 4; ++j) {
            float4 v = *(const float4*)(xr + j * 4);
            xT[d0 + j * 4 + 0][s_l] = v.x; xT[d0 + j * 4 + 1][s_l] = v.y;
            xT[d0 + j * 4 + 2][s_l] = v.z; xT[d0 + j * 4 + 3][s_l] = v.w;
        }
    }
    __syncthreads();
    int c = t >> 3, so = (t & 7) * 8;
    float aa[8] = {}, bb2[8] = {};
    #pragma unroll 8
    for (int d = 0; d < 64; ++d) {
        float wlv = wl[c * 64 + d], wrv = wr[c * 64 + d];
        #pragma unroll
        for (int q = 0; q < 8; ++q) {
            float xv = xT[d][so + q];
            aa[q]  += xv * wlv;
            bb2[q] += xv * wrv;
        }
    }
    #pragma unroll
    for (int q = 0; q < 8; ++q) {
        float wq = wsq[s0 + so + q];
        aa[q] *= wq; bb2[q] *= wq;
    }
    int m = i * 32 + c;
    int s = s0 + so;
    size_t idx = (((size_t)(m >> 4) * 16 + (s >> 5)) * 64 + ((m & 15) | (((s >> 3) & 3) << 4))) * 8;
    {
        unsigned short h[8], l[8];
        #pragma unroll
        for (int q = 0; q < 8; ++q) { h[q] = f2b(aa[q]); l[q] = f2b(aa[q] - b2f(h[q])); }
        *(uint4*)&AHo[idx] = make_uint4((unsigned)h[0] | ((unsigned)h[1] << 16), (unsigned)h[2] | ((unsigned)h[3] << 16),
                                        (unsigned)h[4] | ((unsigned)h[5] << 16), (unsigned)h[6] | ((unsigned)h[7] << 16));
        *(uint4*)&ALo[idx] = make_uint4((unsigned)l[0] | ((unsigned)l[1] << 16), (unsigned)l[2] | ((unsigned)l[3] << 16),
                                        (unsigned)l[4] | ((unsigned)l[5] << 16), (unsigned)l[6] | ((unsigned)l[7] << 16));
    }
    {
        unsigned short h[8], l[8];
        #pragma unroll
        for (int q = 0; q < 8; ++q) { h[q] = f2b(bb2[q]); l[q] = f2b(bb2[q] - b2f(h[q])); }
        *(uint4*)&BHo[idx] = make_uint4((unsigned)h[0] | ((unsigned)h[1] << 16), (unsigned)h[2] | ((unsigned)h[3] << 16),
                                        (unsigned)h[4] | ((unsigned)h[5] << 16), (unsigned)h[6] | ((unsigned)h[7] << 16));
        *(uint4*)&BLo[idx] = make_uint4((unsigned)l[0] | ((unsigned)l[1] << 16), (unsigned)l[2] | ((unsigned)l[3] << 16),
                                        (unsigned)l[4] | ((unsigned)l[5] << 16), (unsigned)l[6] | ((unsigned)l[7] << 16));
    }
}

// ---------------- prep: WpF frag layout [bsel][nb][kstep][lane][8] + bpP ----------------
__global__ __launch_bounds__(256) void prep_wp(const float* __restrict__ Wp,
                                               const float* __restrict__ bp,
                                               unsigned short* __restrict__ WpF,
                                               float* __restrict__ bpP) {
    int gid = blockIdx.x * 256 + threadIdx.x;
    int lane  = gid & 63;
    int kstep = (gid >> 6) & 31;
    int nb    = (gid >> 11) & 15;
    int bsel  = gid >> 15;
    int rl = lane & 15, kg = lane >> 4;
    int urow = nb * 16 + rl;
    int srow = (urow & 1) ? 128 + (urow >> 1) : (urow >> 1);
    int k0 = kstep * 32 + kg * 8;
    const float* src = Wp + (size_t)srow * 1024 + k0;
    unsigned short o[8];
    #pragma unroll
    for (int e = 0; e < 8; ++e) {
        float w = src[e];
        unsigned short h = f2b(w);
        o[e] = bsel ? f2b(w - b2f(h)) : h;
    }
    *(uint4*)&WpF[(size_t)gid * 8] = make_uint4(
        (unsigned)o[0] | ((unsigned)o[1] << 16), (unsigned)o[2] | ((unsigned)o[3] << 16),
        (unsigned)o[4] | ((unsigned)o[5] << 16), (unsigned)o[6] | ((unsigned)o[7] << 16));
    if (blockIdx.x == 0) {
        int tt = threadIdx.x;
        bpP[tt] = bp[(tt & 1) ? 128 + (tt >> 1) : (tt >> 1)];
    }
}

// ---------------- FUSED v2: 256x256 tile, 8 waves (wave tile 64x128), bf16x3 + Wp + SwiGLU ----------------
// LDS 128KB: dbuf 2 x {AH 16K | AL 16K | BH 16K | BL 16K}; pa [16][1024] u32 aliases buf0.
// Epilogue: 4 passes of 16 (i,j) pairs; pass g spilled by waves with (wave&3)==g.
__global__ __launch_bounds__(512, 2) void gemm_fused(const unsigned short* __restrict__ AH,
                                                     const unsigned short* __restrict__ AL,
                                                     const unsigned short* __restrict__ BHm,
                                                     const unsigned short* __restrict__ BLm,
                                                     const unsigned short* __restrict__ WpF,
                                                     const float* __restrict__ bpP,
                                                     float* __restrict__ out) {
    __shared__ __align__(16) unsigned char smem[131072];
    unsigned* pa = (unsigned*)smem;                       // [16][1024] packed hi|lo u32

    const int t = threadIdx.x;
    const int wave = t >> 6, lane = t & 63;
    const int bx = blockIdx.x, by = blockIdx.y;
    const int m0 = bx * 256, n0 = by * 256;
    const int wr = wave & 3;            // A row-group: rows wr*64 .. wr*64+63
    const int wc = wave >> 2;           // B col-group: cols wc*128 .. wc*128+127
    const int kgrp = lane >> 4, rl = lane & 15;
    f32x4 acc[4][8] = {};

    // staging: wave w stages array (w>>1) {AH,AL,BH,BL}, panes (w&1)*8..+7 (1KB frags)
    const unsigned short* srcArr = (wave < 2) ? AH : (wave < 4) ? AL : (wave < 6) ? BHm : BLm;
    const int pbase = (((wave < 4) ? m0 : n0) >> 4) + (wave & 1) * 8;
    const unsigned short* srcBase = srcArr + (size_t)pbase * 8192 + lane * 8;
    unsigned short* dstW = (unsigned short*)smem + (wave >> 1) * 8192 + (wave & 1) * 4096;

    // prologue: stage kt=0 into buf0 (8 GLDS in flight per wave)
    #pragma unroll
    for (int p = 0; p < 8; ++p)
        GLDS(srcBase + (size_t)p * 8192, dstW + p * 512);

    for (int kt = 0; kt < 16; ++kt) {
        if (kt < 15) {
            unsigned short* dst = dstW + ((kt + 1) & 1) * 32768;
            const unsigned short* s2 = srcBase + (size_t)(kt + 1) * 512;
            #pragma unroll
            for (int p = 0; p < 8; ++p)
                GLDS(s2 + (size_t)p * 8192, dst + p * 512);
            asm volatile("s_waitcnt vmcnt(8)" ::: "memory");
        } else {
            asm volatile("s_waitcnt vmcnt(0)" ::: "memory");
        }
        __builtin_amdgcn_s_barrier();
        asm volatile("" ::: "memory");
        const int cb = (kt & 1) * 65536;
        bf16x8 aHf[4], aLf[4];
        #pragma unroll
        for (int mf = 0; mf < 4; ++mf) {
            const int pA = (wr * 4 + mf) * 1024;
            aHf[mf] = *(const bf16x8*)(smem + cb + pA + lane * 16);
            aLf[mf] = *(const bf16x8*)(smem + cb + 16384 + pA + lane * 16);
        }
        __builtin_amdgcn_s_setprio(1);
        #pragma unroll
        for (int nf = 0; nf < 8; ++nf) {
            const int pB = (wc * 8 + nf) * 1024;
            bf16x8 bHf = *(const bf16x8*)(smem + cb + 32768 + pB + lane * 16);
            bf16x8 bLf = *(const bf16x8*)(smem + cb + 49152 + pB + lane * 16);
            #pragma unroll
            for (int mf = 0; mf < 4; ++mf) {
                acc[mf][nf] = __builtin_amdgcn_mfma_f32_16x16x32_bf16(aHf[mf], bHf, acc[mf][nf], 0, 0, 0);
                acc[mf][nf] = __builtin_amdgcn_mfma_f32_16x16x32_bf16(aLf[mf], bHf, acc[mf][nf], 0, 0, 0);
                acc[mf][nf] = __builtin_amdgcn_mfma_f32_16x16x32_bf16(aHf[mf], bLf, acc[mf][nf], 0, 0, 0);
            }
        }
        __builtin_amdgcn_s_setprio(0);
        asm volatile("" ::: "memory");
        __builtin_amdgcn_s_barrier();
        asm volatile("" ::: "memory");
    }

    // ---- 4 epilogue passes of 16 pairs each ----
    for (int g = 0; g < 4; ++g) {
        if (wr == g) {
            // spill this wave's 64x128 quadrant (pairs pl = (mf>>1)*8 + wc*4 + (nf>>1))
            #pragma unroll
            for (int mf = 0; mf < 4; ++mf)
                #pragma unroll
                for (int nf = 0; nf < 8; ++nf) {
                    int pl = ((mf >> 1) << 3) + wc * 4 + (nf >> 1);
                    #pragma unroll
                    for (int r = 0; r < 4; ++r) {
                        int k = (((mf & 1) * 16 + kgrp * 4 + r) << 5) | ((nf & 1) * 16 + rl);
                        float v = acc[mf][nf][r];
                        unsigned short h = f2b(v);
                        unsigned short l = f2b(v - b2f(h));
                        pa[(pl << 10) + (k ^ ((pl & 3) << 3))] = (unsigned)h | ((unsigned)l << 16);
                    }
                }
        }
        __syncthreads();

        f32x4 acc2[2] = {};
        const unsigned* paRow = pa + (rl << 10);
        const int kg8 = kgrp * 8;
        #pragma unroll 4
        for (int ks = 0; ks < 32; ++ks) {
            U4B8 ua0, ua1, aHf, aLf;
            int kb = (ks * 32 + kg8) ^ ((rl & 3) << 3);
            ua0.u4 = *(const uint4*)(paRow + kb);
            ua1.u4 = *(const uint4*)(paRow + kb + 4);
            aHf.u[0] = __builtin_amdgcn_perm(ua0.u[1], ua0.u[0], 0x05040100u);
            aHf.u[1] = __builtin_amdgcn_perm(ua0.u[3], ua0.u[2], 0x05040100u);
            aHf.u[2] = __builtin_amdgcn_perm(ua1.u[1], ua1.u[0], 0x05040100u);
            aHf.u[3] = __builtin_amdgcn_perm(ua1.u[3], ua1.u[2], 0x05040100u);
            aLf.u[0] = __builtin_amdgcn_perm(ua0.u[1], ua0.u[0], 0x07060302u);
            aLf.u[1] = __builtin_amdgcn_perm(ua0.u[3], ua0.u[2], 0x07060302u);
            aLf.u[2] = __builtin_amdgcn_perm(ua1.u[1], ua1.u[0], 0x07060302u);
            aLf.u[3] = __builtin_amdgcn_perm(ua1.u[3], ua1.u[2], 0x07060302u);
            #pragma unroll
            for (int nf2 = 0; nf2 < 2; ++nf2) {
                const int nb = wave * 2 + nf2;
                bf16x8 bHf = *(const bf16x8*)&WpF[(size_t)((nb * 32 + ks) * 64 + lane) * 8];
                bf16x8 bLf = *(const bf16x8*)&WpF[(size_t)(((16 + nb) * 32 + ks) * 64 + lane) * 8];
                acc2[nf2] = __builtin_amdgcn_mfma_f32_16x16x32_bf16(aHf.v, bHf, acc2[nf2], 0, 0, 0);
                acc2[nf2] = __builtin_amdgcn_mfma_f32_16x16x32_bf16(aLf.v, bHf, acc2[nf2], 0, 0, 0);
                acc2[nf2] = __builtin_amdgcn_mfma_f32_16x16x32_bf16(aHf.v, bLf, acc2[nf2], 0, 0, 0);
            }
        }

        // bias + SwiGLU + store for this pass's 16 pairs
        const int parity = rl & 1;
        #pragma unroll
        for (int nf2 = 0; nf2 < 2; ++nf2) {
            const int np = wave * 32 + nf2 * 16 + rl;   // logical u-row (interleaved val/gate)
            const float bias = bpP[np];
            const int ocol = np >> 1;
            #pragma unroll
            for (int r = 0; r < 4; ++r) {
                float own = acc2[nf2][r] + bias;
                float oth = __shfl_xor(own, 1);
                float v = parity ? oth : own;
                float gg = parity ? own : oth;
                float res = v * (gg / (1.0f + expf(-gg)));
                if (parity == (r >> 1)) {
                    int pl2 = kgrp * 4 + r;              // pair index within pass
                    int i = bx * 8 + g * 2 + (pl2 >> 3);
                    int j = by * 8 + (pl2 & 7);
                    out[((size_t)i * 384 + j) * 128 + ocol] = res;
                }
            }
        }
        __syncthreads();
    }
}

extern "C" void kernel_launch(void* const* d_in, const int* in_sizes, int n_in,
                              void* d_out, int out_size, void* d_ws, size_t ws_size,
                              hipStream_t stream) {
    const float* msa  = (const float*)d_in[0];
    const float* ln_g = (const float*)d_in[1];
    const float* ln_b = (const float*)d_in[2];
    const float* Wq   = (const float*)d_in[3];
    const float* Wk   = (const float*)d_in[4];
    const float* qn_g = (const float*)d_in[5];
    const float* qn_b = (const float*)d_in[6];
    const float* kn_g = (const float*)d_in[7];
    const float* kn_b = (const float*)d_in[8];
    const float* lq1  = (const float*)d_in[9];
    const float* lk1  = (const float*)d_in[10];
    const float* lq2  = (const float*)d_in[11];
    const float* lk2  = (const float*)d_in[12];
    const float* Wl   = (const float*)d_in[13];
    const float* Wr   = (const float*)d_in[14];
    const float* Wp   = (const float*)d_in[15];
    const float* bp   = (const float*)d_in[16];
    float* out = (float*)d_out;
    float* ws  = (float*)d_ws;

    float* x = ws + WS_X;
    unsigned short* AHs = (unsigned short*)(ws + WS_AEXT);
    unsigned short* ALs = (unsigned short*)(ws + WS_AEXT + 3145728u);
    unsigned short* BHs = (unsigned short*)(ws + WS_BEXT);
    unsigned short* BLs = (unsigned short*)(ws + WS_BEXT + 3145728u);
    float* qg   = ws + WS_QG;
    float* Sqg  = ws + WS_SQG;
    float* Sqb  = ws + WS_SQB;
    float* part = ws + WS_PART;
    float* wsq  = ws + WS_WSQ;
    float* bpP  = ws + WS_BPP;
    unsigned short* WpF = (unsigned short*)(ws + WS_WPF);

    prep_wp<<<256, 256, 0, stream>>>(Wp, bp, WpF, bpP);
    k1_ln<<<12288, 256, 0, stream>>>(msa, ln_g, ln_b, x);
    k2_q<<<384, 128, 0, stream>>>(x, Wq, qn_g, qn_b, kn_g, kn_b, qg, Sqg, Sqb);
    gemm_k3<<<1536, 256, 0, stream>>>(x, Wk, qg, Sqg, Sqb, part);
    k4_softmax<<<1, 512, 0, stream>>>(part, lq1, lk1, lq2, lk2, wsq);
    k5_ab<<<dim3(384, 8), 256, 0, stream>>>(x, Wl, Wr, wsq, AHs, ALs, BHs, BLs);
    gemm_fused<<<dim3(48, 48), 512, 0, stream>>>(AHs, ALs, BHs, BLs, WpF, bpP, out);
}

// Round 10
// 858.875 us; speedup vs baseline: 1.0860x; 1.0860x over previous
//
#include <hip/hip_runtime.h>
#include <hip/hip_bf16.h>
#include <math.h>

// B=1, S=512, N=384, D=64, H=32, DP=128, DQK=64
// ws layout (float offsets)
#define WS_X        0u          // x f32 [196608][64]                 = 12582912
#define WS_AEXT     12582912u   // AH frag bf16 [768*16][64][8] = 3145728 f, then AL same
#define WS_BEXT     18874368u   // BH, BL same
#define WS_QG       25165824u   // qg [2][384][64] = 49152
#define WS_SQG      25214976u   // [768]
#define WS_SQB      25215744u   // [768]
#define WS_PART     25216512u   // partial dots [2][512][3] = 3072
#define WS_WSQ      25219584u   // [512]
#define WS_BPP      25220096u   // [256]
#define WS_WPF      25220352u   // WpF bf16 frag-layout [2][16][32][64][8] = 262144 f

typedef __attribute__((ext_vector_type(8))) short bf16x8;
typedef __attribute__((ext_vector_type(4))) float f32x4;

union U4B8 { uint4 u4; unsigned u[4]; bf16x8 v; };

__device__ __forceinline__ unsigned short f2b(float x) {
    __hip_bfloat16 b = __float2bfloat16(x);
    return *reinterpret_cast<unsigned short*>(&b);
}
__device__ __forceinline__ float b2f(unsigned short u) {
    __hip_bfloat16 b = *reinterpret_cast<__hip_bfloat16*>(&u);
    return __bfloat162float(b);
}

#define GLDS(g, l) __builtin_amdgcn_global_load_lds(                                   \
    (const __attribute__((address_space(1))) unsigned int*)(g),                        \
    (__attribute__((address_space(3))) unsigned int*)(l), 16, 0, 0)

// ---------------- K1: LayerNorm over D=64, float4-vectorized (16 rows/block) ----------------
__global__ __launch_bounds__(256) void k1_ln(const float* __restrict__ msa,
                                             const float* __restrict__ g,
                                             const float* __restrict__ bb,
                                             float* __restrict__ x) {
    int row = blockIdx.x * 16 + (threadIdx.x >> 4);
    int l16 = threadIdx.x & 15;
    float4 v = ((const float4*)msa)[(size_t)row * 16 + l16];
    float sum = v.x + v.y + v.z + v.w;
    #pragma unroll
    for (int m = 1; m < 16; m <<= 1) sum += __shfl_xor(sum, m);
    float mean = sum * (1.0f / 64.0f);
    float4 dv = make_float4(v.x - mean, v.y - mean, v.z - mean, v.w - mean);
    float sq = dv.x * dv.x + dv.y * dv.y + dv.z * dv.z + dv.w * dv.w;
    #pragma unroll
    for (int m = 1; m < 16; m <<= 1) sq += __shfl_xor(sq, m);
    float r = rsqrtf(sq * (1.0f / 64.0f) + 1e-5f);
    float4 g4 = ((const float4*)g)[l16];
    float4 b4 = ((const float4*)bb)[l16];
    ((float4*)x)[(size_t)row * 16 + l16] = make_float4(
        dv.x * r * g4.x + b4.x, dv.y * r * g4.y + b4.y,
        dv.z * r * g4.z + b4.z, dv.w * r * g4.w + b4.w);
}

// ---------------- K2: q projection + LN, emit qg = qn*kn_g, Sqg, Sqb ----------------
__global__ __launch_bounds__(128) void k2_q(const float* __restrict__ x,
                                            const float* __restrict__ Wq,
                                            const float* __restrict__ qg_,
                                            const float* __restrict__ qb_,
                                            const float* __restrict__ kg_,
                                            const float* __restrict__ kb_,
                                            float* __restrict__ qgOut,
                                            float* __restrict__ SqgOut,
                                            float* __restrict__ SqbOut) {
    int n = blockIdx.x;
    int tt = threadIdx.x >> 6;
    int d = threadIdx.x & 63;
    const float* xr = x + (size_t)n * 64;
    const float* w  = Wq + (size_t)(tt * 64 + d) * 64;
    float acc = 0.f;
    #pragma unroll 8
    for (int dd = 0; dd < 64; ++dd) acc += xr[dd] * w[dd];
    float sum = acc;
    #pragma unroll
    for (int m = 1; m < 64; m <<= 1) sum += __shfl_xor(sum, m);
    float mean = sum * (1.0f / 64.0f);
    float dv = acc - mean;
    float sq = dv * dv;
    #pragma unroll
    for (int m = 1; m < 64; m <<= 1) sq += __shfl_xor(sq, m);
    float r = rsqrtf(sq * (1.0f / 64.0f) + 1e-5f);
    float qnv = dv * r * qg_[d] + qb_[d];
    float qgv = qnv * kg_[d];
    float sb  = qnv * kb_[d];
    float sg  = qgv;
    #pragma unroll
    for (int m = 1; m < 64; m <<= 1) { sg += __shfl_xor(sg, m); sb += __shfl_xor(sb, m); }
    qgOut[(size_t)(tt * 384 + n) * 64 + d] = qgv;
    if (d == 0) { SqgOut[tt * 384 + n] = sg; SqbOut[tt * 384 + n] = sb; }
}

// ---------------- gemm_k3: kraw tile (fp32 GEMM) + LN-dot epilogue -> partials ----------------
__global__ __launch_bounds__(256) void gemm_k3(const float* __restrict__ X,
                                               const float* __restrict__ Wk,
                                               const float* __restrict__ qg,
                                               const float* __restrict__ Sqg,
                                               const float* __restrict__ Sqb,
                                               float* __restrict__ part) {
    __shared__ __align__(16) char smem[65536];
    float (*AsT)[132] = (float(*)[132])smem;
    float (*BsT)[132] = (float(*)[132])(smem + 16896);
    float* kbuf = (float*)smem;   // aliases AsT/BsT after GEMM completes

    int t  = threadIdx.x;
    int m0 = blockIdx.x * 128;
    int s  = m0 / 384;
    int nchunk = (m0 - s * 384) >> 7;
    int tr = t >> 4, tc = t & 15;
    float acc[8][8] = {};
    int rrow = t >> 3;
    int kk   = (t & 7) * 4;
    for (int k0 = 0; k0 < 64; k0 += 32) {
        #pragma unroll
        for (int l = 0; l < 4; ++l) {
            int row = rrow + 32 * l;
            float4 va = *(const float4*)(X + (size_t)(m0 + row) * 64 + k0 + kk);
            AsT[kk + 0][row] = va.x; AsT[kk + 1][row] = va.y;
            AsT[kk + 2][row] = va.z; AsT[kk + 3][row] = va.w;
            float4 vb = *(const float4*)(Wk + (size_t)row * 64 + k0 + kk);
            BsT[kk + 0][row] = vb.x; BsT[kk + 1][row] = vb.y;
            BsT[kk + 2][row] = vb.z; BsT[kk + 3][row] = vb.w;
        }
        __syncthreads();
        #pragma unroll 4
        for (int k = 0; k < 32; ++k) {
            float a[8], b[8];
            *(float4*)&a[0] = *(const float4*)&AsT[k][tr * 8];
            *(float4*)&a[4] = *(const float4*)&AsT[k][tr * 8 + 4];
            *(float4*)&b[0] = *(const float4*)&BsT[k][tc * 8];
            *(float4*)&b[4] = *(const float4*)&BsT[k][tc * 8 + 4];
            #pragma unroll
            for (int q = 0; q < 8; ++q)
                #pragma unroll
                for (int j = 0; j < 8; ++j)
                    acc[q][j] += a[q] * b[j];
        }
        __syncthreads();
    }
    #pragma unroll
    for (int q = 0; q < 8; ++q) {
        int m = tr * 8 + q;
        int swz = (m & 15) << 4;
        int b0 = m * 512 + (((tc * 2) * 16) ^ swz);
        int b1 = m * 512 + (((tc * 2 + 1) * 16) ^ swz);
        *(float4*)((char*)kbuf + b0) = make_float4(acc[q][0], acc[q][1], acc[q][2], acc[q][3]);
        *(float4*)((char*)kbuf + b1) = make_float4(acc[q][4], acc[q][5], acc[q][6], acc[q][7]);
    }
    __syncthreads();
    int r  = t & 127;
    int tt = t >> 7;
    int n  = nchunk * 128 + r;
    const char* base = (const char*)kbuf + r * 512;
    const float4* qgp = (const float4*)(qg + ((size_t)(tt * 384 + n)) * 64);
    int swz = (r & 15) << 4;
    float s1 = 0.f, s2 = 0.f, s3 = 0.f;
    #pragma unroll
    for (int i = 0; i < 16; ++i) {
        float4 kv = *(const float4*)(base + ((((tt * 16 + i) * 16) ^ swz)));
        float4 qv = qgp[i];
        s1 += kv.x + kv.y + kv.z + kv.w;
        s2 += kv.x * kv.x + kv.y * kv.y + kv.z * kv.z + kv.w * kv.w;
        s3 += kv.x * qv.x + kv.y * qv.y + kv.z * qv.z + kv.w * qv.w;
    }
    float mu  = s1 * (1.0f / 64.0f);
    float var = s2 * (1.0f / 64.0f) - mu * mu;
    float rln = rsqrtf(var + 1e-5f);
    float dot = rln * (s3 - mu * Sqg[tt * 384 + n]) + Sqb[tt * 384 + n];
    #pragma unroll
    for (int m = 1; m < 64; m <<= 1) dot += __shfl_xor(dot, m);
    __syncthreads();
    if ((t & 63) == 0) kbuf[t >> 6] = dot;
    __syncthreads();
    if (t == 0) part[((size_t)0 * 512 + s) * 3 + nchunk] = kbuf[0] + kbuf[1];
    if (t == 1) part[((size_t)1 * 512 + s) * 3 + nchunk] = kbuf[2] + kbuf[3];
}

// ---------------- K4: lambda, softmax over s, sqrt weights (reads partials) ----------------
__global__ __launch_bounds__(512) void k4_softmax(const float* __restrict__ part,
                                                  const float* __restrict__ lq1,
                                                  const float* __restrict__ lk1,
                                                  const float* __restrict__ lq2,
                                                  const float* __restrict__ lk2,
                                                  float* __restrict__ wsq) {
    int s = threadIdx.x;
    float l1 = 0.f, l2 = 0.f;
    for (int i = 0; i < 64; ++i) { l1 += lq1[i] * lk1[i]; l2 += lq2[i] * lk2[i]; }
    float lam = expf(l1) - expf(l2) + 1.0f;
    const float c = 0.125f / 384.0f;
    float a0 = (part[s * 3] + part[s * 3 + 1] + part[s * 3 + 2]) * c;
    float a1 = (part[(512 + s) * 3] + part[(512 + s) * 3 + 1] + part[(512 + s) * 3 + 2]) * c;
    float v = a0 - lam * a1;
    __shared__ float red[512];
    red[s] = v;
    __syncthreads();
    for (int off = 256; off > 0; off >>= 1) {
        if (s < off) red[s] = fmaxf(red[s], red[s + off]);
        __syncthreads();
    }
    float mx = red[0];
    __syncthreads();
    float e = expf(v - mx);
    red[s] = e;
    __syncthreads();
    for (int off = 256; off > 0; off >>= 1) {
        if (s < off) red[s] += red[s + off];
        __syncthreads();
    }
    wsq[s] = sqrtf(e / red[0] + 1e-32f);
}

// ---------------- K5: build A/B hi-lo splits in MFMA-frag-native layout ----------------
__global__ __launch_bounds__(256) void k5_ab(const float* __restrict__ x,
                                             const float* __restrict__ Wl,
                                             const float* __restrict__ Wr,
                                             const float* __restrict__ wsq,
                                             unsigned short* __restrict__ AHo,
                                             unsigned short* __restrict__ ALo,
                                             unsigned short* __restrict__ BHo,
                                             unsigned short* __restrict__ BLo) {
    int i  = blockIdx.x;
    int s0 = blockIdx.y * 64;
    int t  = threadIdx.x;
    __shared__ __align__(16) float wl[2048], wr[2048];
    __shared__ float xT[64][69];
    ((float4*)wl)[t * 2]     = ((const float4*)Wl)[t * 2];
    ((float4*)wl)[t * 2 + 1] = ((const float4*)Wl)[t * 2 + 1];
    ((float4*)wr)[t * 2]     = ((const float4*)Wr)[t * 2];
    ((float4*)wr)[t * 2 + 1] = ((const float4*)Wr)[t * 2 + 1];
    {
        int s_l = t >> 2, d0 = (t & 3) * 16;
        const float* xr = x + ((size_t)(s0 + s_l) * 384 + i) * 64 + d0;
        #pragma unroll
        for (int j = 0; j < 4; ++j) {
            float4 v = *(const float4*)(xr + j * 4);
            xT[d0 + j * 4 + 0][s_l] = v.x; xT[d0 + j * 4 + 1][s_l] = v.y;
            xT[d0 + j * 4 + 2][s_l] = v.z; xT[d0 + j * 4 + 3][s_l] = v.w;
        }
    }
    __syncthreads();
    int c = t >> 3, so = (t & 7) * 8;
    float aa[8] = {}, bb2[8] = {};
    #pragma unroll 8
    for (int d = 0; d < 64; ++d) {
        float wlv = wl[c * 64 + d], wrv = wr[c * 64 + d];
        #pragma unroll
        for (int q = 0; q < 8; ++q) {
            float xv = xT[d][so + q];
            aa[q]  += xv * wlv;
            bb2[q] += xv * wrv;
        }
    }
    #pragma unroll
    for (int q = 0; q < 8; ++q) {
        float wq = wsq[s0 + so + q];
        aa[q] *= wq; bb2[q] *= wq;
    }
    int m = i * 32 + c;
    int s = s0 + so;
    size_t idx = (((size_t)(m >> 4) * 16 + (s >> 5)) * 64 + ((m & 15) | (((s >> 3) & 3) << 4))) * 8;
    {
        unsigned short h[8], l[8];
        #pragma unroll
        for (int q = 0; q < 8; ++q) { h[q] = f2b(aa[q]); l[q] = f2b(aa[q] - b2f(h[q])); }
        *(uint4*)&AHo[idx] = make_uint4((unsigned)h[0] | ((unsigned)h[1] << 16), (unsigned)h[2] | ((unsigned)h[3] << 16),
                                        (unsigned)h[4] | ((unsigned)h[5] << 16), (unsigned)h[6] | ((unsigned)h[7] << 16));
        *(uint4*)&ALo[idx] = make_uint4((unsigned)l[0] | ((unsigned)l[1] << 16), (unsigned)l[2] | ((unsigned)l[3] << 16),
                                        (unsigned)l[4] | ((unsigned)l[5] << 16), (unsigned)l[6] | ((unsigned)l[7] << 16));
    }
    {
        unsigned short h[8], l[8];
        #pragma unroll
        for (int q = 0; q < 8; ++q) { h[q] = f2b(bb2[q]); l[q] = f2b(bb2[q] - b2f(h[q])); }
        *(uint4*)&BHo[idx] = make_uint4((unsigned)h[0] | ((unsigned)h[1] << 16), (unsigned)h[2] | ((unsigned)h[3] << 16),
                                        (unsigned)h[4] | ((unsigned)h[5] << 16), (unsigned)h[6] | ((unsigned)h[7] << 16));
        *(uint4*)&BLo[idx] = make_uint4((unsigned)l[0] | ((unsigned)l[1] << 16), (unsigned)l[2] | ((unsigned)l[3] << 16),
                                        (unsigned)l[4] | ((unsigned)l[5] << 16), (unsigned)l[6] | ((unsigned)l[7] << 16));
    }
}

// ---------------- prep: WpF frag layout [bsel][nb][kstep][lane][8] + bpP ----------------
__global__ __launch_bounds__(256) void prep_wp(const float* __restrict__ Wp,
                                               const float* __restrict__ bp,
                                               unsigned short* __restrict__ WpF,
                                               float* __restrict__ bpP) {
    int gid = blockIdx.x * 256 + threadIdx.x;
    int lane  = gid & 63;
    int kstep = (gid >> 6) & 31;
    int nb    = (gid >> 11) & 15;
    int bsel  = gid >> 15;
    int rl = lane & 15, kg = lane >> 4;
    int urow = nb * 16 + rl;
    int srow = (urow & 1) ? 128 + (urow >> 1) : (urow >> 1);
    int k0 = kstep * 32 + kg * 8;
    const float* src = Wp + (size_t)srow * 1024 + k0;
    unsigned short o[8];
    #pragma unroll
    for (int e = 0; e < 8; ++e) {
        float w = src[e];
        unsigned short h = f2b(w);
        o[e] = bsel ? f2b(w - b2f(h)) : h;
    }
    *(uint4*)&WpF[(size_t)gid * 8] = make_uint4(
        (unsigned)o[0] | ((unsigned)o[1] << 16), (unsigned)o[2] | ((unsigned)o[3] << 16),
        (unsigned)o[4] | ((unsigned)o[5] << 16), (unsigned)o[6] | ((unsigned)o[7] << 16));
    if (blockIdx.x == 0) {
        int tt = threadIdx.x;
        bpP[tt] = bp[(tt & 1) ? 128 + (tt >> 1) : (tt >> 1)];
    }
}

// ---------------- FUSED v4: A global->VGPR (reg-dbuf), B via GLDS dbuf, round-6 sync ----------------
// LDS 64KB: B dbuf 2 x {BH 8K | BL 8K} = 32KB; pa [16][1024] u32 (64KB) aliases all.
// ONE __syncthreads per kt (proven round-6 schedule; no manual waitcnt).
__global__ __launch_bounds__(256) void gemm_fused(const unsigned short* __restrict__ AH,
                                                  const unsigned short* __restrict__ AL,
                                                  const unsigned short* __restrict__ BHm,
                                                  const unsigned short* __restrict__ BLm,
                                                  const unsigned short* __restrict__ WpF,
                                                  const float* __restrict__ bpP,
                                                  float* __restrict__ out) {
    __shared__ __align__(16) unsigned char smem[65536];
    unsigned* pa = (unsigned*)smem;                       // [16][1024] packed hi|lo u32

    const int t = threadIdx.x;
    const int wave = t >> 6, lane = t & 63;
    const int bx = blockIdx.x, by = blockIdx.y;
    const int m0 = bx * 128, n0 = by * 128;
    const int wm = (wave & 1) * 64, wn = (wave >> 1) * 64;
    const int kgrp = lane >> 4, rl = lane & 15;
    f32x4 acc[4][4] = {};

    // A: direct global->VGPR, frag-native; wave's 4 panels start at (m0+wm)/16
    const unsigned short* aHb = AH + (size_t)((m0 + wm) >> 4) * 8192 + lane * 8;
    const unsigned short* aLb = AL + (size_t)((m0 + wm) >> 4) * 8192 + lane * 8;
    // B staging: wave w stages (w<2 ? BH : BL), panes (w&1)*4 .. +3
    const unsigned short* bArr = (wave < 2) ? BHm : BLm;
    const unsigned short* bSrc = bArr + (size_t)((n0 >> 4) + (wave & 1) * 4) * 8192 + lane * 8;
    const int dstOffB = (wave >> 1) * 8192 + (wave & 1) * 4096;   // bytes within a 16KB buffer

    bf16x8 aHr[2][4], aLr[2][4];
    // prologue: GLDS B(0) into buf0; A(0) into reg set 0
    #pragma unroll
    for (int p = 0; p < 4; ++p)
        GLDS(bSrc + (size_t)p * 8192, (unsigned short*)(smem + dstOffB + p * 1024));
    #pragma unroll
    for (int f = 0; f < 4; ++f) {
        aHr[0][f] = *(const bf16x8*)(aHb + (size_t)f * 8192);
        aLr[0][f] = *(const bf16x8*)(aLb + (size_t)f * 8192);
    }
    __syncthreads();

    #pragma unroll 2
    for (int kt = 0; kt < 16; ++kt) {
        const int cur = kt & 1, nxt = cur ^ 1;
        if (kt < 15) {
            // issue next B stage (4 GLDS) into the other buffer + A(kt+1) into other reg set;
            // both overlap this kt's MFMA burst; the end-of-kt __syncthreads drains them.
            const unsigned short* s2 = bSrc + (size_t)(kt + 1) * 512;
            #pragma unroll
            for (int p = 0; p < 4; ++p)
                GLDS(s2 + (size_t)p * 8192, (unsigned short*)(smem + nxt * 16384 + dstOffB + p * 1024));
            #pragma unroll
            for (int f = 0; f < 4; ++f) {
                aHr[nxt][f] = *(const bf16x8*)(aHb + (size_t)f * 8192 + (kt + 1) * 512);
                aLr[nxt][f] = *(const bf16x8*)(aLb + (size_t)f * 8192 + (kt + 1) * 512);
            }
        }
        const int cb = cur * 16384;
        bf16x8 bHf[4], bLf[4];
        #pragma unroll
        for (int f = 0; f < 4; ++f) {
            const int pB = ((wn >> 4) + f) * 1024;
            bHf[f] = *(const bf16x8*)(smem + cb + pB + lane * 16);
            bLf[f] = *(const bf16x8*)(smem + cb + 8192 + pB + lane * 16);
        }
        __builtin_amdgcn_s_setprio(1);
        #pragma unroll
        for (int mf = 0; mf < 4; ++mf)
            #pragma unroll
            for (int nf = 0; nf < 4; ++nf) {
                acc[mf][nf] = __builtin_amdgcn_mfma_f32_16x16x32_bf16(aHr[cur][mf], bHf[nf], acc[mf][nf], 0, 0, 0);
                acc[mf][nf] = __builtin_amdgcn_mfma_f32_16x16x32_bf16(aLr[cur][mf], bHf[nf], acc[mf][nf], 0, 0, 0);
                acc[mf][nf] = __builtin_amdgcn_mfma_f32_16x16x32_bf16(aHr[cur][mf], bLf[nf], acc[mf][nf], 0, 0, 0);
            }
        __builtin_amdgcn_s_setprio(0);
        __syncthreads();   // drains GLDS(kt+1)+A-loads (vmcnt0) and orders buf reuse
    }

    // ---- spill outer tile to pa as packed hi|lo bf16 (XOR-swizzled, 4-way) ----
    #pragma unroll
    for (int mf = 0; mf < 4; ++mf) {
        #pragma unroll
        for (int nf = 0; nf < 4; ++nf) {
            #pragma unroll
            for (int r = 0; r < 4; ++r) {
                int mloc = wm + mf * 16 + kgrp * 4 + r;
                int nloc = wn + nf * 16 + rl;
                int p = ((mloc >> 5) << 2) | (nloc >> 5);
                int k = ((mloc & 31) << 5) | (nloc & 31);
                float v = acc[mf][nf][r];
                unsigned short h = f2b(v);
                unsigned short l = f2b(v - b2f(h));
                pa[(p << 10) + (k ^ ((p & 3) << 3))] = (unsigned)h | ((unsigned)l << 16);
            }
        }
    }
    __syncthreads();

    // ---- epilogue GEMM: [16 pairs] x WpF^T, single pass over all 3 sections ----
    f32x4 acc2[4] = {};
    const unsigned* paRow = pa + (rl << 10);
    const int kg8 = kgrp * 8;
    #pragma unroll 4
    for (int ks = 0; ks < 32; ++ks) {
        U4B8 ua0, ua1, aHf, aLf;
        int kb = (ks * 32 + kg8) ^ ((rl & 3) << 3);
        ua0.u4 = *(const uint4*)(paRow + kb);
        ua1.u4 = *(const uint4*)(paRow + kb + 4);
        aHf.u[0] = __builtin_amdgcn_perm(ua0.u[1], ua0.u[0], 0x05040100u);
        aHf.u[1] = __builtin_amdgcn_perm(ua0.u[3], ua0.u[2], 0x05040100u);
        aHf.u[2] = __builtin_amdgcn_perm(ua1.u[1], ua1.u[0], 0x05040100u);
        aHf.u[3] = __builtin_amdgcn_perm(ua1.u[3], ua1.u[2], 0x05040100u);
        aLf.u[0] = __builtin_amdgcn_perm(ua0.u[1], ua0.u[0], 0x07060302u);
        aLf.u[1] = __builtin_amdgcn_perm(ua0.u[3], ua0.u[2], 0x07060302u);
        aLf.u[2] = __builtin_amdgcn_perm(ua1.u[1], ua1.u[0], 0x07060302u);
        aLf.u[3] = __builtin_amdgcn_perm(ua1.u[3], ua1.u[2], 0x07060302u);
        bf16x8 bHf[4], bLf[4];
        #pragma unroll
        for (int nf = 0; nf < 4; ++nf) {
            const int nb = wave * 4 + nf;
            bHf[nf] = *(const bf16x8*)&WpF[(size_t)((nb * 32 + ks) * 64 + lane) * 8];
            bLf[nf] = *(const bf16x8*)&WpF[(size_t)(((16 + nb) * 32 + ks) * 64 + lane) * 8];
        }
        __builtin_amdgcn_s_setprio(1);
        #pragma unroll
        for (int nf = 0; nf < 4; ++nf) {
            acc2[nf] = __builtin_amdgcn_mfma_f32_16x16x32_bf16(aHf.v, bHf[nf], acc2[nf], 0, 0, 0);
            acc2[nf] = __builtin_amdgcn_mfma_f32_16x16x32_bf16(aLf.v, bHf[nf], acc2[nf], 0, 0, 0);
            acc2[nf] = __builtin_amdgcn_mfma_f32_16x16x32_bf16(aHf.v, bLf[nf], acc2[nf], 0, 0, 0);
        }
        __builtin_amdgcn_s_setprio(0);
    }

    // ---- bias + SwiGLU + store ----
    const int parity = rl & 1;
    #pragma unroll
    for (int nf = 0; nf < 4; ++nf) {
        const int np = wave * 64 + nf * 16 + rl;
        const float bias = bpP[np];
        const int ocol = np >> 1;
        #pragma unroll
        for (int r = 0; r < 4; ++r) {
            float own = acc2[nf][r] + bias;
            float oth = __shfl_xor(own, 1);
            float v = parity ? oth : own;
            float g = parity ? own : oth;
            float res = v * (g / (1.0f + expf(-g)));
            if (parity == (r >> 1)) {
                int p = kgrp * 4 + r;
                int i = bx * 4 + (p >> 2);
                int j = by * 4 + (p & 3);
                out[((size_t)i * 384 + j) * 128 + ocol] = res;
            }
        }
    }
}

extern "C" void kernel_launch(void* const* d_in, const int* in_sizes, int n_in,
                              void* d_out, int out_size, void* d_ws, size_t ws_size,
                              hipStream_t stream) {
    const float* msa  = (const float*)d_in[0];
    const float* ln_g = (const float*)d_in[1];
    const float* ln_b = (const float*)d_in[2];
    const float* Wq   = (const float*)d_in[3];
    const float* Wk   = (const float*)d_in[4];
    const float* qn_g = (const float*)d_in[5];
    const float* qn_b = (const float*)d_in[6];
    const float* kn_g = (const float*)d_in[7];
    const float* kn_b = (const float*)d_in[8];
    const float* lq1  = (const float*)d_in[9];
    const float* lk1  = (const float*)d_in[10];
    const float* lq2  = (const float*)d_in[11];
    const float* lk2  = (const float*)d_in[12];
    const float* Wl   = (const float*)d_in[13];
    const float* Wr   = (const float*)d_in[14];
    const float* Wp   = (const float*)d_in[15];
    const float* bp   = (const float*)d_in[16];
    float* out = (float*)d_out;
    float* ws  = (float*)d_ws;

    float* x = ws + WS_X;
    unsigned short* AHs = (unsigned short*)(ws + WS_AEXT);
    unsigned short* ALs = (unsigned short*)(ws + WS_AEXT + 3145728u);
    unsigned short* BHs = (unsigned short*)(ws + WS_BEXT);
    unsigned short* BLs = (unsigned short*)(ws + WS_BEXT + 3145728u);
    float* qg   = ws + WS_QG;
    float* Sqg  = ws + WS_SQG;
    float* Sqb  = ws + WS_SQB;
    float* part = ws + WS_PART;
    float* wsq  = ws + WS_WSQ;
    float* bpP  = ws + WS_BPP;
    unsigned short* WpF = (unsigned short*)(ws + WS_WPF);

    prep_wp<<<256, 256, 0, stream>>>(Wp, bp, WpF, bpP);
    k1_ln<<<12288, 256, 0, stream>>>(msa, ln_g, ln_b, x);
    k2_q<<<384, 128, 0, stream>>>(x, Wq, qn_g, qn_b, kn_g, kn_b, qg, Sqg, Sqb);
    gemm_k3<<<1536, 256, 0, stream>>>(x, Wk, qg, Sqg, Sqb, part);
    k4_softmax<<<1, 512, 0, stream>>>(part, lq1, lk1, lq2, lk2, wsq);
    k5_ab<<<dim3(384, 8), 256, 0, stream>>>(x, Wl, Wr, wsq, AHs, ALs, BHs, BLs);
    gemm_fused<<<dim3(96, 96), 256, 0, stream>>>(AHs, ALs, BHs, BLs, WpF, bpP, out);
}